// Round 1
// baseline (951.299 us; speedup 1.0000x reference)
//
#include <hip/hip_runtime.h>

typedef __bf16 bf16;
typedef __attribute__((ext_vector_type(8))) __bf16 bf16x8;
typedef __attribute__((ext_vector_type(4))) __bf16 bf16x4;
typedef __attribute__((ext_vector_type(2))) __bf16 bf16x2;
typedef __attribute__((ext_vector_type(4))) float f32x4;
typedef __attribute__((ext_vector_type(4))) unsigned int u32x4;

#define TOKENS 3136
#define CC 768
#define S196 196
#define M_ROWS 25088   // 16*8*196
#define BATCH 16

__device__ __forceinline__ float bf2f(bf16 x) { return (float)x; }
__device__ __forceinline__ bf16 f2bf(float x) { return (bf16)x; }

__device__ __forceinline__ float gelu_exact(float x) {
    return 0.5f * x * (1.0f + erff(x * 0.70710678118654752f));
}

__device__ __forceinline__ unsigned int packbf(float a, float b) {
    bf16x2 v; v[0] = (bf16)a; v[1] = (bf16)b;
    return __builtin_bit_cast(unsigned int, v);
}

// async global->LDS, 16B per lane; LDS dest = wave-uniform base + lane*16
#define GLOAD_LDS16(gp, lp) \
    __builtin_amdgcn_global_load_lds((const __attribute__((address_space(1))) void*)(gp), \
                                     (__attribute__((address_space(3))) void*)(lp), 16, 0, 0)

// ---------------------------------------------------------------------------
// Weight transpose + bf16 convert: Wt[n][k] = W[k][n]   (fp32 input)
// ---------------------------------------------------------------------------
__global__ __launch_bounds__(256)
void transpose_w(const float* __restrict__ W, bf16* __restrict__ Wt, int K, int N)
{
    __shared__ float tle[32][33];
    int k0 = blockIdx.x * 32, n0 = blockIdx.y * 32;
    int tx = threadIdx.x & 31, ty = threadIdx.x >> 5;   // 8 rows of 32
    for (int r = ty; r < 32; r += 8)
        tle[r][tx] = W[(long)(k0 + r) * N + n0 + tx];
    __syncthreads();
    for (int r = ty; r < 32; r += 8)
        Wt[(long)(n0 + r) * K + k0 + tx] = f2bf(tle[tx][r]);
}

// ---------------------------------------------------------------------------
// Bias convert (fp32 -> bf16) into packed ws array.
// Layout: [bq_d(768) | bkv_a(1536) | bq_a(768) | bkv_d(1536) | bp_d | bp_a]
// ---------------------------------------------------------------------------
__global__ __launch_bounds__(256)
void conv_bias(const float* b0, const float* b1, const float* b2,
               const float* b3, const float* b4, const float* b5,
               bf16* __restrict__ dst)
{
    const float* srcs[6] = {b0, b1, b2, b3, b4, b5};
    const int sizes[6]   = {768, 1536, 768, 1536, 768, 768};
    const int offs[6]    = {0, 768, 2304, 3072, 4608, 5376};
    int which = blockIdx.x;
    const float* s = srcs[which];
    int n = sizes[which];
    bf16* d = dst + offs[which];
    for (int i = threadIdx.x; i < n; i += 256)
        d[i] = f2bf(s[i]);
}

// ---------------------------------------------------------------------------
// Reorder x_in (b, nt, nh, nw, t, c) fp32 -> bf16 x_a / x_d rows
// ---------------------------------------------------------------------------
__global__ __launch_bounds__(256)
void reorder_split(const float* __restrict__ x_in, bf16* __restrict__ xa,
                   bf16* __restrict__ xd)
{
    long idx = (long)blockIdx.x * 256 + threadIdx.x;
    const long total = (long)BATCH * 16 * S196 * 96;
    if (idx >= total) return;
    int  c8  = (int)(idx % 96) * 8;
    long row = idx / 96;
    int  s   = (int)(row % S196);
    long r2  = row / S196;
    int  tt  = (int)(r2 & 15);
    int  b   = (int)(r2 >> 4);
    int  nt  = tt >> 2, t = tt & 3;
    int  nh  = s / 14,  nw = s % 14;
    long src  = ((long)b * TOKENS + ((nt * 14 + nh) * 14 + nw) * 4 + t) * CC + c8;
    bf16* dst = (tt & 1) ? xd : xa;
    long doff = ((long)(b * 8 + (tt >> 1)) * S196 + s) * CC + c8;
    const float* sp = x_in + src;
    f32x4 a = *(const f32x4*)sp;
    f32x4 c = *(const f32x4*)(sp + 4);
    bf16x8 v;
    v[0] = f2bf(a[0]); v[1] = f2bf(a[1]); v[2] = f2bf(a[2]); v[3] = f2bf(a[3]);
    v[4] = f2bf(c[0]); v[5] = f2bf(c[1]); v[6] = f2bf(c[2]); v[7] = f2bf(c[3]);
    *(bf16x8*)(dst + doff) = v;
}

// ---------------------------------------------------------------------------
// Row-sum helper: sum of 768 bf16 channels, one wave per row.
// ---------------------------------------------------------------------------
__device__ __forceinline__ float row_sum768(const bf16* __restrict__ p, int lane)
{
    float s = 0.f;
    bf16x8 v = *(const bf16x8*)(p + lane * 8);
    #pragma unroll
    for (int j = 0; j < 8; ++j) s += bf2f(v[j]);
    if (lane < 32) {
        bf16x8 w = *(const bf16x8*)(p + 512 + lane * 8);
        #pragma unroll
        for (int j = 0; j < 8; ++j) s += bf2f(w[j]);
    }
    #pragma unroll
    for (int off = 32; off; off >>= 1) s += __shfl_xor(s, off, 64);
    return s;
}

__global__ __launch_bounds__(256)
void pool_ad(const bf16* __restrict__ xa, const bf16* __restrict__ xd,
             float* __restrict__ pool0)
{
    int id = blockIdx.x * 4 + (threadIdx.x >> 6);
    int lane = threadIdx.x & 63;
    float sa = row_sum768(xa + (long)id * CC, lane);
    float sd = row_sum768(xd + (long)id * CC, lane);
    if (lane == 0) pool0[id] = (sa + sd) * (0.5f / 768.0f);
}

__global__ __launch_bounds__(256)
void out_final(const bf16* __restrict__ xa, const bf16* __restrict__ xd,
               const float* __restrict__ pool0, float* __restrict__ out)
{
    int id = blockIdx.x * 4 + (threadIdx.x >> 6);
    int lane = threadIdx.x & 63;
    float sa = row_sum768(xa + (long)id * CC, lane);
    float sd = row_sum768(xd + (long)id * CC, lane);
    if (lane == 0) {
        out[id]          = pool0[id] - sa * (1.0f / 768.0f);
        out[M_ROWS + id] = sd * (1.0f / 768.0f);
    }
}

// ---------------------------------------------------------------------------
// GEMM v2: C = A(MxK) @ Bt(NxK)^T + bias.
// BM=256 x BN=128 x BK=64 tile, 512 threads = 8 waves (4M x 2N), 64x64/wave.
// Triple-buffered LDS (144 KB), prefetch distance 2 K-tiles, ONE raw
// s_barrier + ONE counted s_waitcnt vmcnt(6) per K-tile (never a full drain
// in steady state).  XOR chunk swizzle: LDS position (r, c16) holds global
// chunk c16 ^ (r&7); applied on the global SOURCE address at staging
// (global_load_lds dest must stay linear) and on the ds_read address.
// EPI: 0 -> C = x ; 1 -> C = res - gelu(x) ; 2 -> C = res + gelu(x)
// ---------------------------------------------------------------------------
template<int EPI>
__global__ __launch_bounds__(512, 1)
void gemm_bt(const bf16* __restrict__ A, const bf16* __restrict__ Bt,
             const bf16* __restrict__ bias, const bf16* __restrict__ res,
             bf16* __restrict__ C, int ldc, int K, int mTiles, int nTiles)
{
    constexpr int BM = 256, BN = 128, BK = 64, NBUF = 3;
    __shared__ alignas(16) bf16 sA[NBUF][BM * BK];   // 3 x 32 KB
    __shared__ alignas(16) bf16 sB[NBUF][BN * BK];   // 3 x 16 KB
    const int tid  = threadIdx.x;
    const int lane = tid & 63, wave = tid >> 6;
    const int wm   = wave >> 1, wn = wave & 1;       // 4 x 2 wave grid
    const int quad = lane >> 4, l16 = lane & 15;

    // GROUP_M swizzle for L2/L3 locality
    const int GM = 16;
    int pid   = blockIdx.x;
    int group = GM * nTiles;
    int gid   = pid / group;
    int rem   = pid - gid * group;
    int first = gid * GM;
    int gm    = (mTiles - first < GM) ? (mTiles - first) : GM;
    int bm    = first + rem % gm;
    int bn    = rem / gm;

    const long m0 = (long)bm * BM;
    const long n0 = (long)bn * BN;
    const int  NKT = K / BK;

    // staging constants: lane covers LDS chunk (row q*8 + rsub, cpos = lane&7);
    // that slot must hold global chunk clog = cpos ^ (row&7) = (lane&7)^rsub.
    const int rsub = lane >> 3;
    const int clog = (lane & 7) ^ rsub;

    f32x4 acc[4][4] = {};

    #define STAGE_A(buf, kt2, j) do { \
        int q_ = (j) * 8 + wave; \
        const bf16* g_ = A + (m0 + q_ * 8 + rsub) * (long)K + (kt2) * BK + clog * 8; \
        GLOAD_LDS16(g_, &sA[buf][q_ * 512]); } while (0)
    #define STAGE_B(buf, kt2, j) do { \
        int q_ = (j) * 8 + wave; \
        const bf16* g_ = Bt + (n0 + q_ * 8 + rsub) * (long)K + (kt2) * BK + clog * 8; \
        GLOAD_LDS16(g_, &sB[buf][q_ * 512]); } while (0)

    // prologue: stage K-tiles 0 and 1 (6 loads each per thread)
    STAGE_A(0, 0, 0); STAGE_A(0, 0, 1); STAGE_A(0, 0, 2); STAGE_A(0, 0, 3);
    STAGE_B(0, 0, 0); STAGE_B(0, 0, 1);
    STAGE_A(1, 1, 0); STAGE_A(1, 1, 1); STAGE_A(1, 1, 2); STAGE_A(1, 1, 3);
    STAGE_B(1, 1, 0); STAGE_B(1, 1, 1);
    asm volatile("s_waitcnt vmcnt(6)" ::: "memory");   // K-tile 0 landed
    __builtin_amdgcn_s_barrier();

    // one K-slice (kk = 0/1) of one K-tile: 8 ds_read_b128 + 16 MFMA
    auto compute = [&](int buf, int kk) {
        bf16x8 af[4], bfr[4];
        #pragma unroll
        for (int mi = 0; mi < 4; ++mi) {
            int ra = wm * 64 + mi * 16 + l16;
            int cs = (kk * 4 + quad) ^ (ra & 7);
            af[mi] = *(const bf16x8*)(&sA[buf][ra * 64 + cs * 8]);
        }
        #pragma unroll
        for (int ni = 0; ni < 4; ++ni) {
            int rb = wn * 64 + ni * 16 + l16;
            int cs = (kk * 4 + quad) ^ (rb & 7);
            bfr[ni] = *(const bf16x8*)(&sB[buf][rb * 64 + cs * 8]);
        }
        __builtin_amdgcn_s_setprio(1);
        #pragma unroll
        for (int mi = 0; mi < 4; ++mi)
            #pragma unroll
            for (int ni = 0; ni < 4; ++ni)
                acc[mi][ni] = __builtin_amdgcn_mfma_f32_16x16x32_bf16(af[mi], bfr[ni], acc[mi][ni], 0, 0, 0);
        __builtin_amdgcn_s_setprio(0);
    };

    int cur = 0;
    for (int kt = 0; kt < NKT; ++kt) {
        int nxt2 = cur + 2; if (nxt2 >= NBUF) nxt2 -= NBUF;   // buf for kt+2
        const bool doStage = (kt + 2 < NKT);

        // phase 0: issue half the next-next stage, compute kk=0
        if (doStage) { STAGE_A(nxt2, kt + 2, 0); STAGE_A(nxt2, kt + 2, 1); STAGE_B(nxt2, kt + 2, 0); }
        compute(cur, 0);
        // phase 1: issue the rest, compute kk=1
        if (doStage) { STAGE_A(nxt2, kt + 2, 2); STAGE_A(nxt2, kt + 2, 3); STAGE_B(nxt2, kt + 2, 1); }
        compute(cur, 1);

        if (kt + 2 < NKT) {
            // counted: kt+1's 6 loads retired, kt+2's 6 stay in flight
            asm volatile("s_waitcnt vmcnt(6)" ::: "memory");
            __builtin_amdgcn_s_barrier();
        } else if (kt + 1 < NKT) {
            // tail: only kt+1's loads outstanding
            asm volatile("s_waitcnt vmcnt(0)" ::: "memory");
            __builtin_amdgcn_s_barrier();
        }
        cur = cur + 1; if (cur == NBUF) cur = 0;
    }
    #undef STAGE_A
    #undef STAGE_B

    // Epilogue. D layout: col = lane&15 (n), row = quad*4 + r (m)
    #pragma unroll
    for (int mi = 0; mi < 4; ++mi) {
        #pragma unroll
        for (int ni = 0; ni < 4; ++ni) {
            int mg = (int)m0 + wm * 64 + mi * 16 + quad * 4;
            int ng = (int)n0 + wn * 64 + ni * 16 + l16;
            float bn_ = bf2f(bias[ng]);
            #pragma unroll
            for (int r = 0; r < 4; ++r) {
                float x = acc[mi][ni][r] + bn_;
                long off = (long)(mg + r) * ldc + ng;
                if (EPI == 0)      C[off] = f2bf(x);
                else if (EPI == 1) C[off] = f2bf(bf2f(res[off]) - gelu_exact(x));
                else               C[off] = f2bf(bf2f(res[off]) + gelu_exact(x));
            }
        }
    }
}

// ---------------------------------------------------------------------------
// MFMA attention, stride-parameterized. One block per (head h, instance bj).
// ---------------------------------------------------------------------------
#define KSTR 72
#define VSTR 264

__global__ __launch_bounds__(256)
void attn_mfma(const bf16* __restrict__ Q, int ldq,
               const bf16* __restrict__ KV, int ldkv,
               bf16* __restrict__ O)
{
    const int h  = blockIdx.x;   // 12
    const int bj = blockIdx.y;   // 128
    __shared__ alignas(16) bf16 Ks[208 * KSTR];
    __shared__ alignas(16) bf16 Vt[64 * VSTR];
    const int tid = threadIdx.x, lane = tid & 63, wave = tid >> 6;
    const int quad = lane >> 4, l16 = lane & 15;

    const bf16* qg = Q  + (long)bj * S196 * ldq  + h * 64;
    const bf16* kg = KV + (long)bj * S196 * ldkv + h * 64;
    const bf16* vg = kg + CC;

    for (int i = tid; i < 208 * 8; i += 256) {
        int r = i >> 3, c8 = (i & 7) * 8;
        bf16x8 v = {};
        if (r < S196) v = *(const bf16x8*)(kg + (long)r * ldkv + c8);
        *(bf16x8*)(Ks + r * KSTR + c8) = v;
    }
    for (int i = tid; i < 256 * 8; i += 256) {
        int g   = i >> 6;
        int c8  = (g & 7) * 8;
        int tok = (g >> 3) * 64 + (i & 63);
        bf16x8 v = {};
        if (tok < S196) v = *(const bf16x8*)(vg + (long)tok * ldkv + c8);
        #pragma unroll
        for (int j = 0; j < 8; ++j)
            Vt[(c8 + j) * VSTR + tok] = v[j];
    }
    __syncthreads();

    for (int qt = wave; qt < 13; qt += 4) {
        int qrow = qt * 16 + l16; if (qrow > 195) qrow = 195;
        const bf16* qrp = qg + (long)qrow * ldq + quad * 8;
        bf16x8 qf0 = *(const bf16x8*)(qrp);
        bf16x8 qf1 = *(const bf16x8*)(qrp + 32);

        f32x4 st[13];
        #pragma unroll
        for (int rt = 0; rt < 13; ++rt) st[rt] = (f32x4){0.f, 0.f, 0.f, 0.f};
        #pragma unroll
        for (int rt = 0; rt < 13; ++rt) {
            const bf16* kb = Ks + (rt * 16 + l16) * KSTR + quad * 8;
            bf16x8 kf0 = *(const bf16x8*)(kb);
            bf16x8 kf1 = *(const bf16x8*)(kb + 32);
            st[rt] = __builtin_amdgcn_mfma_f32_16x16x32_bf16(kf0, qf0, st[rt], 0, 0, 0);
            st[rt] = __builtin_amdgcn_mfma_f32_16x16x32_bf16(kf1, qf1, st[rt], 0, 0, 0);
        }

        const float SC = 0.125f;
        #pragma unroll
        for (int rt = 0; rt < 13; ++rt) {
            st[rt][0] *= SC; st[rt][1] *= SC; st[rt][2] *= SC; st[rt][3] *= SC;
        }
        if (quad != 0)
            st[12] = (f32x4){-1e30f, -1e30f, -1e30f, -1e30f};

        float m = -1e30f;
        #pragma unroll
        for (int rt = 0; rt < 13; ++rt)
            m = fmaxf(m, fmaxf(fmaxf(st[rt][0], st[rt][1]), fmaxf(st[rt][2], st[rt][3])));
        m = fmaxf(m, __shfl_xor(m, 16, 64));
        m = fmaxf(m, __shfl_xor(m, 32, 64));
        float sum = 0.f;
        #pragma unroll
        for (int rt = 0; rt < 13; ++rt) {
            st[rt][0] = __expf(st[rt][0] - m);
            st[rt][1] = __expf(st[rt][1] - m);
            st[rt][2] = __expf(st[rt][2] - m);
            st[rt][3] = __expf(st[rt][3] - m);
            sum += st[rt][0] + st[rt][1] + st[rt][2] + st[rt][3];
        }
        sum += __shfl_xor(sum, 16, 64);
        sum += __shfl_xor(sum, 32, 64);
        float inv = 1.0f / sum;

        unsigned int pk[13][2];
        #pragma unroll
        for (int rt = 0; rt < 13; ++rt) {
            pk[rt][0] = packbf(st[rt][0] * inv, st[rt][1] * inv);
            pk[rt][1] = packbf(st[rt][2] * inv, st[rt][3] * inv);
        }

        f32x4 ot[4];
        #pragma unroll
        for (int dt = 0; dt < 4; ++dt) ot[dt] = (f32x4){0.f, 0.f, 0.f, 0.f};
        #pragma unroll
        for (int c = 0; c < 7; ++c) {
            u32x4 fp;
            #pragma unroll
            for (int jp = 0; jp < 4; ++jp) {
                int jh = jp >> 1, rp = jp & 1;
                int srcb = ((((quad & 1) << 1) + jh) << 6) | (l16 << 2);
                int a = __builtin_amdgcn_ds_bpermute(srcb, (int)pk[2 * c][rp]);
                int b = (c < 6) ? __builtin_amdgcn_ds_bpermute(srcb, (int)pk[2 * c + 1][rp]) : 0;
                fp[jp] = (quad >> 1) ? (unsigned int)b : (unsigned int)a;
            }
            bf16x8 pB = __builtin_bit_cast(bf16x8, fp);
            #pragma unroll
            for (int dt = 0; dt < 4; ++dt) {
                bf16x8 vf = *(const bf16x8*)(Vt + (dt * 16 + l16) * VSTR + c * 32 + quad * 8);
                ot[dt] = __builtin_amdgcn_mfma_f32_16x16x32_bf16(vf, pB, ot[dt], 0, 0, 0);
            }
        }

        int token = qt * 16 + l16;
        if (token < S196) {
            bf16* op = O + ((long)bj * S196 + token) * CC + h * 64 + quad * 4;
            #pragma unroll
            for (int dt = 0; dt < 4; ++dt) {
                bf16x4 v;
                v[0] = f2bf(ot[dt][0]); v[1] = f2bf(ot[dt][1]);
                v[2] = f2bf(ot[dt][2]); v[3] = f2bf(ot[dt][3]);
                *(bf16x4*)(op + dt * 16) = v;
            }
        }
    }
}

// ---------------------------------------------------------------------------
extern "C" void kernel_launch(void* const* d_in, const int* in_sizes, int n_in,
                              void* d_out, int out_size, void* d_ws, size_t ws_size,
                              hipStream_t stream)
{
    const float* x_in  = (const float*)d_in[0];
    const float* Wq_d  = (const float*)d_in[1];
    const float* bq_d  = (const float*)d_in[2];
    const float* Wkv_a = (const float*)d_in[3];
    const float* bkv_a = (const float*)d_in[4];
    const float* Wq_a  = (const float*)d_in[5];
    const float* bq_a  = (const float*)d_in[6];
    const float* Wkv_d = (const float*)d_in[7];
    const float* bkv_d = (const float*)d_in[8];
    const float* Wp_d  = (const float*)d_in[9];
    const float* bp_d  = (const float*)d_in[10];
    const float* Wp_a  = (const float*)d_in[11];
    const float* bp_a  = (const float*)d_in[12];
    float* out = (float*)d_out;

    char* w = (char*)d_ws;
    auto alloc = [&](size_t elems) {
        bf16* p = (bf16*)w;
        w += ((elems * 2 + 255) / 256) * 256;
        return p;
    };
    bf16* biasAll = alloc(6144);
    bf16* WtQd  = alloc((size_t)768 * 768);
    bf16* WtACat= alloc((size_t)2304 * 768);   // [Wkv_a^T ; Wq_a^T]
    bf16* WtKd  = alloc((size_t)1536 * 768);
    bf16* WtPd  = alloc((size_t)768 * 768);
    bf16* WtPa  = alloc((size_t)768 * 768);
    bf16* xa    = alloc((size_t)M_ROWS * 768);
    bf16* xd    = alloc((size_t)M_ROWS * 768);
    bf16* Qb    = alloc((size_t)M_ROWS * 768);
    bf16* QKVa  = alloc((size_t)M_ROWS * 2304); // cols 0..1535 kv, 1536..2303 q_a
    bf16* Ob    = alloc((size_t)M_ROWS * 768);
    float* pool0 = (float*)w; w += ((size_t)M_ROWS * 4 + 255) / 256 * 256;

    dim3 blk(256);
    dim3 blk512(512);
    transpose_w<<<dim3(24, 24), blk, 0, stream>>>(Wq_d,  WtQd, 768, 768);
    transpose_w<<<dim3(24, 48), blk, 0, stream>>>(Wkv_a, WtACat, 768, 1536);
    transpose_w<<<dim3(24, 24), blk, 0, stream>>>(Wq_a,  WtACat + (size_t)1536 * 768, 768, 768);
    transpose_w<<<dim3(24, 48), blk, 0, stream>>>(Wkv_d, WtKd, 768, 1536);
    transpose_w<<<dim3(24, 24), blk, 0, stream>>>(Wp_d,  WtPd, 768, 768);
    transpose_w<<<dim3(24, 24), blk, 0, stream>>>(Wp_a,  WtPa, 768, 768);
    conv_bias<<<dim3(6), blk, 0, stream>>>(bq_d, bkv_a, bq_a, bkv_d, bp_d, bp_a, biasAll);

    long total_chunks = (long)BATCH * 16 * S196 * 96;
    int  rblocks = (int)((total_chunks + 255) / 256);
    reorder_split<<<rblocks, blk, 0, stream>>>(x_in, xa, xd);
    pool_ad<<<M_ROWS / 4, blk, 0, stream>>>(xa, xd, pool0);

    const bf16* Bq_d   = biasAll;
    const bf16* Bkva_qa= biasAll + 768;   // 2304-wide: bkv_a | bq_a
    const bf16* Bkv_d  = biasAll + 3072;
    const bf16* Bp_d   = biasAll + 4608;
    const bf16* Bp_a   = biasAll + 5376;

    // BM=256 -> mTiles = 98; BN=128 -> nTiles: 6 (768), 12 (1536), 18 (2304)
    // Phase 1: Qb = xd@Wq_d ; QKVa = xa@[Wkv_a|Wq_a]
    gemm_bt<0><<<dim3(98 * 6),  blk512, 0, stream>>>(xd, WtQd,  Bq_d,    nullptr, Qb,   768,  768, 98, 6);
    gemm_bt<0><<<dim3(98 * 18), blk512, 0, stream>>>(xa, WtACat, Bkva_qa, nullptr, QKVa, 2304, 768, 98, 18);
    attn_mfma<<<dim3(12, 128), blk, 0, stream>>>(Qb, 768, QKVa, 2304, Ob);
    gemm_bt<1><<<dim3(98 * 6),  blk512, 0, stream>>>(Ob, WtPd, Bp_d, xd, xd, 768, 768, 98, 6);

    // Phase 2: kv_d overwrites QKVa cols 0..1535 (kv_a is dead after attn1)
    gemm_bt<0><<<dim3(98 * 12), blk512, 0, stream>>>(xd, WtKd, Bkv_d, nullptr, QKVa, 2304, 768, 98, 12);
    attn_mfma<<<dim3(12, 128), blk, 0, stream>>>(QKVa + 1536, 2304, QKVa, 2304, Ob);
    gemm_bt<2><<<dim3(98 * 6),  blk512, 0, stream>>>(Ob, WtPa, Bp_a, xa, xa, 768, 768, 98, 6);

    out_final<<<M_ROWS / 4, blk, 0, stream>>>(xa, xd, pool0, out);
}

// Round 2
// 936.773 us; speedup vs baseline: 1.0155x; 1.0155x over previous
//
#include <hip/hip_runtime.h>

typedef __bf16 bf16;
typedef __attribute__((ext_vector_type(8))) __bf16 bf16x8;
typedef __attribute__((ext_vector_type(4))) __bf16 bf16x4;
typedef __attribute__((ext_vector_type(2))) __bf16 bf16x2;
typedef __attribute__((ext_vector_type(4))) float f32x4;
typedef __attribute__((ext_vector_type(4))) unsigned int u32x4;

#define TOKENS 3136
#define CC 768
#define S196 196
#define M_ROWS 25088   // 16*8*196
#define BATCH 16

__device__ __forceinline__ float bf2f(bf16 x) { return (float)x; }
__device__ __forceinline__ bf16 f2bf(float x) { return (bf16)x; }

__device__ __forceinline__ float gelu_exact(float x) {
    return 0.5f * x * (1.0f + erff(x * 0.70710678118654752f));
}

__device__ __forceinline__ unsigned int packbf(float a, float b) {
    bf16x2 v; v[0] = (bf16)a; v[1] = (bf16)b;
    return __builtin_bit_cast(unsigned int, v);
}

// async global->LDS, 16B per lane; LDS dest = wave-uniform base + lane*16
#define GLOAD_LDS16(gp, lp) \
    __builtin_amdgcn_global_load_lds((const __attribute__((address_space(1))) void*)(gp), \
                                     (__attribute__((address_space(3))) void*)(lp), 16, 0, 0)

// ---------------------------------------------------------------------------
// Weight transpose + bf16 convert: Wt[n][k] = W[k][n]   (fp32 input)
// ---------------------------------------------------------------------------
__global__ __launch_bounds__(256)
void transpose_w(const float* __restrict__ W, bf16* __restrict__ Wt, int K, int N)
{
    __shared__ float tle[32][33];
    int k0 = blockIdx.x * 32, n0 = blockIdx.y * 32;
    int tx = threadIdx.x & 31, ty = threadIdx.x >> 5;   // 8 rows of 32
    for (int r = ty; r < 32; r += 8)
        tle[r][tx] = W[(long)(k0 + r) * N + n0 + tx];
    __syncthreads();
    for (int r = ty; r < 32; r += 8)
        Wt[(long)(n0 + r) * K + k0 + tx] = f2bf(tle[tx][r]);
}

// ---------------------------------------------------------------------------
// Bias convert (fp32 -> bf16) into packed ws array.
// Layout: [bq_d(768) | bkv_a(1536) | bq_a(768) | bkv_d(1536) | bp_d | bp_a]
// ---------------------------------------------------------------------------
__global__ __launch_bounds__(256)
void conv_bias(const float* b0, const float* b1, const float* b2,
               const float* b3, const float* b4, const float* b5,
               bf16* __restrict__ dst)
{
    const float* srcs[6] = {b0, b1, b2, b3, b4, b5};
    const int sizes[6]   = {768, 1536, 768, 1536, 768, 768};
    const int offs[6]    = {0, 768, 2304, 3072, 4608, 5376};
    int which = blockIdx.x;
    const float* s = srcs[which];
    int n = sizes[which];
    bf16* d = dst + offs[which];
    for (int i = threadIdx.x; i < n; i += 256)
        d[i] = f2bf(s[i]);
}

// ---------------------------------------------------------------------------
// Reorder x_in (b, nt, nh, nw, t, c) fp32 -> bf16 x_a / x_d rows
// ---------------------------------------------------------------------------
__global__ __launch_bounds__(256)
void reorder_split(const float* __restrict__ x_in, bf16* __restrict__ xa,
                   bf16* __restrict__ xd)
{
    long idx = (long)blockIdx.x * 256 + threadIdx.x;
    const long total = (long)BATCH * 16 * S196 * 96;
    if (idx >= total) return;
    int  c8  = (int)(idx % 96) * 8;
    long row = idx / 96;
    int  s   = (int)(row % S196);
    long r2  = row / S196;
    int  tt  = (int)(r2 & 15);
    int  b   = (int)(r2 >> 4);
    int  nt  = tt >> 2, t = tt & 3;
    int  nh  = s / 14,  nw = s % 14;
    long src  = ((long)b * TOKENS + ((nt * 14 + nh) * 14 + nw) * 4 + t) * CC + c8;
    bf16* dst = (tt & 1) ? xd : xa;
    long doff = ((long)(b * 8 + (tt >> 1)) * S196 + s) * CC + c8;
    const float* sp = x_in + src;
    f32x4 a = *(const f32x4*)sp;
    f32x4 c = *(const f32x4*)(sp + 4);
    bf16x8 v;
    v[0] = f2bf(a[0]); v[1] = f2bf(a[1]); v[2] = f2bf(a[2]); v[3] = f2bf(a[3]);
    v[4] = f2bf(c[0]); v[5] = f2bf(c[1]); v[6] = f2bf(c[2]); v[7] = f2bf(c[3]);
    *(bf16x8*)(dst + doff) = v;
}

// ---------------------------------------------------------------------------
// Row-sum helper: sum of 768 bf16 channels, one wave per row.
// ---------------------------------------------------------------------------
__device__ __forceinline__ float row_sum768(const bf16* __restrict__ p, int lane)
{
    float s = 0.f;
    bf16x8 v = *(const bf16x8*)(p + lane * 8);
    #pragma unroll
    for (int j = 0; j < 8; ++j) s += bf2f(v[j]);
    if (lane < 32) {
        bf16x8 w = *(const bf16x8*)(p + 512 + lane * 8);
        #pragma unroll
        for (int j = 0; j < 8; ++j) s += bf2f(w[j]);
    }
    #pragma unroll
    for (int off = 32; off; off >>= 1) s += __shfl_xor(s, off, 64);
    return s;
}

__global__ __launch_bounds__(256)
void pool_ad(const bf16* __restrict__ xa, const bf16* __restrict__ xd,
             float* __restrict__ pool0)
{
    int id = blockIdx.x * 4 + (threadIdx.x >> 6);
    int lane = threadIdx.x & 63;
    float sa = row_sum768(xa + (long)id * CC, lane);
    float sd = row_sum768(xd + (long)id * CC, lane);
    if (lane == 0) pool0[id] = (sa + sd) * (0.5f / 768.0f);
}

__global__ __launch_bounds__(256)
void out_final(const bf16* __restrict__ xa, const bf16* __restrict__ xd,
               const float* __restrict__ pool0, float* __restrict__ out)
{
    int id = blockIdx.x * 4 + (threadIdx.x >> 6);
    int lane = threadIdx.x & 63;
    float sa = row_sum768(xa + (long)id * CC, lane);
    float sd = row_sum768(xd + (long)id * CC, lane);
    if (lane == 0) {
        out[id]          = pool0[id] - sa * (1.0f / 768.0f);
        out[M_ROWS + id] = sd * (1.0f / 768.0f);
    }
}

// ---------------------------------------------------------------------------
// GEMM v3 (m201-style 8-phase): C = A(MxK=768) @ Bt(NxK)^T + bias.
// BM=BN=256, BK=64, 512 threads = 8 waves (2M x 4N), per-wave 128x64 output
// (8x4 frags).  LDS = 4 half-slots per operand, each 256 rows x 32 k = 16 KB
// (halves along K) -> 128 KB total.  Slot ring: half (t,kk) lives in slot
// (2t+kk)&3, reused by (t+2,kk).
// 4 phases per K-tile t:  ph0=(h0,kk0) ph1=(h1,kk0) ph2=(h0,kk1) ph3=(h1,kk1)
//   phase = { ds_read frags ; stage 1 half-tile (2 gload_lds) ; s_barrier ;
//             setprio(1) 16 MFMA setprio(0) ; [vmcnt] ; s_barrier }
// Stage schedule (always >=1 barrier after the slot's last reader):
//   ph0: (t+1,Ak1)  ph1: (t+1,Bk1)  ph2: (t+2,Ak0)  ph3: (t+2,Bk0)
// Waits (counted, never 0 mid-loop):
//   end ph1: vmcnt(8) gates this block's kk1 reads (4 newer halves allowed)
//   end ph3: vmcnt(8) gates next block's kk0 reads
//   tails: vmcnt(4)/vmcnt(0) as staging runs out (derived per block).
// Bank swizzle (2-way = free): slot pos (row, s) holds global k-chunk
// s ^ (row&3) ^ ((row>>2)&3); involution applied on pre-swizzled global
// source at stage time (gload_lds dest stays linear) and on ds_read addr.
// EPI: 0 -> C = x ; 1 -> C = res - gelu(x) ; 2 -> C = res + gelu(x)
// ---------------------------------------------------------------------------
template<int EPI>
__global__ __launch_bounds__(512, 2)
void gemm_bt(const bf16* __restrict__ A, const bf16* __restrict__ Bt,
             const bf16* __restrict__ bias, const bf16* __restrict__ res,
             bf16* __restrict__ C, int ldc, int mTiles, int nTiles)
{
    constexpr int K = 768, NKT = 12;          // all GEMMs in this net: K=768
    __shared__ alignas(16) bf16 sA[4][8192];  // 4 x 16 KB A half-slots
    __shared__ alignas(16) bf16 sB[4][8192];  // 4 x 16 KB B half-slots
    const int tid  = threadIdx.x;
    const int lane = tid & 63, wave = tid >> 6;
    const int wm   = wave >> 2, wn = wave & 3;   // 2M x 4N wave grid
    const int quad = lane >> 4, l16 = lane & 15;

    // GROUP_M swizzle for L2 locality
    const int GM = 8;
    int pid   = blockIdx.x;
    int group = GM * nTiles;
    int gid   = pid / group;
    int rem   = pid - gid * group;
    int first = gid * GM;
    int gm    = (mTiles - first < GM) ? (mTiles - first) : GM;
    int bm    = first + rem % gm;
    int bn    = rem / gm;

    const long m0 = (long)bm * 256;
    const long n0 = (long)bn * 256;

    // ---- per-thread ds_read offsets (elements, within a half-slot) ----
    // row = base + l16 with base % 16 == 0  =>  swizzle f(row) depends only
    // on l16:  f = (l16&3) ^ (l16>>2);  chunk position read = quad ^ f.
    const int fl    = (l16 & 3) ^ (l16 >> 2);
    const int aoffA = (wm * 128 + l16) * 32 + ((quad ^ fl) * 8);
    const int aoffB = (wn * 64  + l16) * 32 + ((quad ^ fl) * 8);

    // ---- per-thread staging constants ----
    // load j covers LDS chunks g = (j*8+wave)*64 + lane ; r = g>>2, pos = g&3;
    // global chunk needed = pos ^ (r&3) ^ ((r>>2)&3)
    //                     = (lane&3) ^ ((lane>>2)&3) ^ quad   (j-independent)
    const int  cch = (lane & 3) ^ ((lane >> 2) & 3) ^ quad;
    const int  r0  = wave * 16 + (lane >> 2);
    const int  r1  = (8 + wave) * 16 + (lane >> 2);
    const long so0 = (long)r0 * K + cch * 8;   // + base + t*64 + kk*32
    const long so1 = (long)r1 * K + cch * 8;
    const int  ld0 = wave * 512, ld1 = (8 + wave) * 512;
    const bf16* Ab = A  + m0 * K;
    const bf16* Bb = Bt + n0 * K;

    f32x4 acc[8][4] = {};

    #define STG_A(slot, koff) do { \
        GLOAD_LDS16(Ab + (koff) + so0, &sA[slot][ld0]); \
        GLOAD_LDS16(Ab + (koff) + so1, &sA[slot][ld1]); } while (0)
    #define STG_B(slot, koff) do { \
        GLOAD_LDS16(Bb + (koff) + so0, &sB[slot][ld0]); \
        GLOAD_LDS16(Bb + (koff) + so1, &sB[slot][ld1]); } while (0)

    // ---- prologue: halves (0,Ak0)(0,Bk0)(0,Ak1)(0,Bk1)(1,Ak0)(1,Bk0) ----
    STG_A(0, 0);  STG_B(0, 0);
    STG_A(1, 32); STG_B(1, 32);
    STG_A(2, 64); STG_B(2, 64);
    asm volatile("s_waitcnt vmcnt(8)" ::: "memory");   // (0,k0) A+B landed
    __builtin_amdgcn_s_barrier();

    #define MFMA16(H) do { \
        __builtin_amdgcn_s_setprio(1); \
        _Pragma("unroll") \
        for (int mf = 0; mf < 4; ++mf) \
            _Pragma("unroll") \
            for (int nf = 0; nf < 4; ++nf) \
                acc[(H)*4 + mf][nf] = __builtin_amdgcn_mfma_f32_16x16x32_bf16( \
                    a[mf], b[nf], acc[(H)*4 + mf][nf], 0, 0, 0); \
        __builtin_amdgcn_s_setprio(0); } while (0)

    #pragma unroll 2
    for (int t = 0; t < NKT; ++t) {
        const int sl0 = (2 * t) & 3;        // kk0 slots (this block)
        const int sl1 = (2 * t + 1) & 3;    // kk1 slots
        const int slN = (2 * t + 3) & 3;    // (t+1) kk1 slots
        bf16x8 a[4], b[4];

        // ---- ph0: (h0, kk0) ----
        #pragma unroll
        for (int mf = 0; mf < 4; ++mf) a[mf] = *(const bf16x8*)(&sA[sl0][mf * 512 + aoffA]);
        #pragma unroll
        for (int nf = 0; nf < 4; ++nf) b[nf] = *(const bf16x8*)(&sB[sl0][nf * 512 + aoffB]);
        if (t + 1 < NKT) STG_A(slN, (t + 1) * 64 + 32);
        __builtin_amdgcn_s_barrier();
        __builtin_amdgcn_sched_barrier(0);
        MFMA16(0);
        __builtin_amdgcn_s_barrier();

        // ---- ph1: (h1, kk0), B reused ----
        #pragma unroll
        for (int mf = 0; mf < 4; ++mf) a[mf] = *(const bf16x8*)(&sA[sl0][2048 + mf * 512 + aoffA]);
        if (t + 1 < NKT) STG_B(slN, (t + 1) * 64 + 32);
        __builtin_amdgcn_s_barrier();
        __builtin_amdgcn_sched_barrier(0);
        MFMA16(1);
        if (t + 1 < NKT) asm volatile("s_waitcnt vmcnt(8)" ::: "memory");
        else             asm volatile("s_waitcnt vmcnt(0)" ::: "memory");
        __builtin_amdgcn_s_barrier();

        // ---- ph2: (h0, kk1) ----
        #pragma unroll
        for (int mf = 0; mf < 4; ++mf) a[mf] = *(const bf16x8*)(&sA[sl1][mf * 512 + aoffA]);
        #pragma unroll
        for (int nf = 0; nf < 4; ++nf) b[nf] = *(const bf16x8*)(&sB[sl1][nf * 512 + aoffB]);
        if (t + 2 < NKT) STG_A(sl0, (t + 2) * 64);
        __builtin_amdgcn_s_barrier();
        __builtin_amdgcn_sched_barrier(0);
        MFMA16(0);
        __builtin_amdgcn_s_barrier();

        // ---- ph3: (h1, kk1), B reused ----
        #pragma unroll
        for (int mf = 0; mf < 4; ++mf) a[mf] = *(const bf16x8*)(&sA[sl1][2048 + mf * 512 + aoffA]);
        if (t + 2 < NKT) STG_B(sl0, (t + 2) * 64);
        __builtin_amdgcn_s_barrier();
        __builtin_amdgcn_sched_barrier(0);
        MFMA16(1);
        if      (t + 2 < NKT) asm volatile("s_waitcnt vmcnt(8)" ::: "memory");
        else if (t + 1 < NKT) asm volatile("s_waitcnt vmcnt(4)" ::: "memory");
        __builtin_amdgcn_s_barrier();
    }
    #undef STG_A
    #undef STG_B
    #undef MFMA16

    // Epilogue. Frag D layout: col = l16 (n), row = quad*4 + r (m)
    #pragma unroll
    for (int mf = 0; mf < 8; ++mf) {
        #pragma unroll
        for (int nf = 0; nf < 4; ++nf) {
            int mg = (int)m0 + wm * 128 + mf * 16 + quad * 4;
            int ng = (int)n0 + wn * 64 + nf * 16 + l16;
            float bn_ = bf2f(bias[ng]);
            #pragma unroll
            for (int r = 0; r < 4; ++r) {
                float x = acc[mf][nf][r] + bn_;
                long off = (long)(mg + r) * ldc + ng;
                if (EPI == 0)      C[off] = f2bf(x);
                else if (EPI == 1) C[off] = f2bf(bf2f(res[off]) - gelu_exact(x));
                else               C[off] = f2bf(bf2f(res[off]) + gelu_exact(x));
            }
        }
    }
}

// ---------------------------------------------------------------------------
// MFMA attention, stride-parameterized. One block per (head h, instance bj).
// ---------------------------------------------------------------------------
#define KSTR 72
#define VSTR 264

__global__ __launch_bounds__(256)
void attn_mfma(const bf16* __restrict__ Q, int ldq,
               const bf16* __restrict__ KV, int ldkv,
               bf16* __restrict__ O)
{
    const int h  = blockIdx.x;   // 12
    const int bj = blockIdx.y;   // 128
    __shared__ alignas(16) bf16 Ks[208 * KSTR];
    __shared__ alignas(16) bf16 Vt[64 * VSTR];
    const int tid = threadIdx.x, lane = tid & 63, wave = tid >> 6;
    const int quad = lane >> 4, l16 = lane & 15;

    const bf16* qg = Q  + (long)bj * S196 * ldq  + h * 64;
    const bf16* kg = KV + (long)bj * S196 * ldkv + h * 64;
    const bf16* vg = kg + CC;

    for (int i = tid; i < 208 * 8; i += 256) {
        int r = i >> 3, c8 = (i & 7) * 8;
        bf16x8 v = {};
        if (r < S196) v = *(const bf16x8*)(kg + (long)r * ldkv + c8);
        *(bf16x8*)(Ks + r * KSTR + c8) = v;
    }
    for (int i = tid; i < 256 * 8; i += 256) {
        int g   = i >> 6;
        int c8  = (g & 7) * 8;
        int tok = (g >> 3) * 64 + (i & 63);
        bf16x8 v = {};
        if (tok < S196) v = *(const bf16x8*)(vg + (long)tok * ldkv + c8);
        #pragma unroll
        for (int j = 0; j < 8; ++j)
            Vt[(c8 + j) * VSTR + tok] = v[j];
    }
    __syncthreads();

    for (int qt = wave; qt < 13; qt += 4) {
        int qrow = qt * 16 + l16; if (qrow > 195) qrow = 195;
        const bf16* qrp = qg + (long)qrow * ldq + quad * 8;
        bf16x8 qf0 = *(const bf16x8*)(qrp);
        bf16x8 qf1 = *(const bf16x8*)(qrp + 32);

        f32x4 st[13];
        #pragma unroll
        for (int rt = 0; rt < 13; ++rt) st[rt] = (f32x4){0.f, 0.f, 0.f, 0.f};
        #pragma unroll
        for (int rt = 0; rt < 13; ++rt) {
            const bf16* kb = Ks + (rt * 16 + l16) * KSTR + quad * 8;
            bf16x8 kf0 = *(const bf16x8*)(kb);
            bf16x8 kf1 = *(const bf16x8*)(kb + 32);
            st[rt] = __builtin_amdgcn_mfma_f32_16x16x32_bf16(kf0, qf0, st[rt], 0, 0, 0);
            st[rt] = __builtin_amdgcn_mfma_f32_16x16x32_bf16(kf1, qf1, st[rt], 0, 0, 0);
        }

        const float SC = 0.125f;
        #pragma unroll
        for (int rt = 0; rt < 13; ++rt) {
            st[rt][0] *= SC; st[rt][1] *= SC; st[rt][2] *= SC; st[rt][3] *= SC;
        }
        if (quad != 0)
            st[12] = (f32x4){-1e30f, -1e30f, -1e30f, -1e30f};

        float m = -1e30f;
        #pragma unroll
        for (int rt = 0; rt < 13; ++rt)
            m = fmaxf(m, fmaxf(fmaxf(st[rt][0], st[rt][1]), fmaxf(st[rt][2], st[rt][3])));
        m = fmaxf(m, __shfl_xor(m, 16, 64));
        m = fmaxf(m, __shfl_xor(m, 32, 64));
        float sum = 0.f;
        #pragma unroll
        for (int rt = 0; rt < 13; ++rt) {
            st[rt][0] = __expf(st[rt][0] - m);
            st[rt][1] = __expf(st[rt][1] - m);
            st[rt][2] = __expf(st[rt][2] - m);
            st[rt][3] = __expf(st[rt][3] - m);
            sum += st[rt][0] + st[rt][1] + st[rt][2] + st[rt][3];
        }
        sum += __shfl_xor(sum, 16, 64);
        sum += __shfl_xor(sum, 32, 64);
        float inv = 1.0f / sum;

        unsigned int pk[13][2];
        #pragma unroll
        for (int rt = 0; rt < 13; ++rt) {
            pk[rt][0] = packbf(st[rt][0] * inv, st[rt][1] * inv);
            pk[rt][1] = packbf(st[rt][2] * inv, st[rt][3] * inv);
        }

        f32x4 ot[4];
        #pragma unroll
        for (int dt = 0; dt < 4; ++dt) ot[dt] = (f32x4){0.f, 0.f, 0.f, 0.f};
        #pragma unroll
        for (int c = 0; c < 7; ++c) {
            u32x4 fp;
            #pragma unroll
            for (int jp = 0; jp < 4; ++jp) {
                int jh = jp >> 1, rp = jp & 1;
                int srcb = ((((quad & 1) << 1) + jh) << 6) | (l16 << 2);
                int a = __builtin_amdgcn_ds_bpermute(srcb, (int)pk[2 * c][rp]);
                int b = (c < 6) ? __builtin_amdgcn_ds_bpermute(srcb, (int)pk[2 * c + 1][rp]) : 0;
                fp[jp] = (quad >> 1) ? (unsigned int)b : (unsigned int)a;
            }
            bf16x8 pB = __builtin_bit_cast(bf16x8, fp);
            #pragma unroll
            for (int dt = 0; dt < 4; ++dt) {
                bf16x8 vf = *(const bf16x8*)(Vt + (dt * 16 + l16) * VSTR + c * 32 + quad * 8);
                ot[dt] = __builtin_amdgcn_mfma_f32_16x16x32_bf16(vf, pB, ot[dt], 0, 0, 0);
            }
        }

        int token = qt * 16 + l16;
        if (token < S196) {
            bf16* op = O + ((long)bj * S196 + token) * CC + h * 64 + quad * 4;
            #pragma unroll
            for (int dt = 0; dt < 4; ++dt) {
                bf16x4 v;
                v[0] = f2bf(ot[dt][0]); v[1] = f2bf(ot[dt][1]);
                v[2] = f2bf(ot[dt][2]); v[3] = f2bf(ot[dt][3]);
                *(bf16x4*)(op + dt * 16) = v;
            }
        }
    }
}

// ---------------------------------------------------------------------------
extern "C" void kernel_launch(void* const* d_in, const int* in_sizes, int n_in,
                              void* d_out, int out_size, void* d_ws, size_t ws_size,
                              hipStream_t stream)
{
    const float* x_in  = (const float*)d_in[0];
    const float* Wq_d  = (const float*)d_in[1];
    const float* bq_d  = (const float*)d_in[2];
    const float* Wkv_a = (const float*)d_in[3];
    const float* bkv_a = (const float*)d_in[4];
    const float* Wq_a  = (const float*)d_in[5];
    const float* bq_a  = (const float*)d_in[6];
    const float* Wkv_d = (const float*)d_in[7];
    const float* bkv_d = (const float*)d_in[8];
    const float* Wp_d  = (const float*)d_in[9];
    const float* bp_d  = (const float*)d_in[10];
    const float* Wp_a  = (const float*)d_in[11];
    const float* bp_a  = (const float*)d_in[12];
    float* out = (float*)d_out;

    char* w = (char*)d_ws;
    auto alloc = [&](size_t elems) {
        bf16* p = (bf16*)w;
        w += ((elems * 2 + 255) / 256) * 256;
        return p;
    };
    bf16* biasAll = alloc(6144);
    bf16* WtQd  = alloc((size_t)768 * 768);
    bf16* WtACat= alloc((size_t)2304 * 768);   // [Wkv_a^T ; Wq_a^T]
    bf16* WtKd  = alloc((size_t)1536 * 768);
    bf16* WtPd  = alloc((size_t)768 * 768);
    bf16* WtPa  = alloc((size_t)768 * 768);
    bf16* xa    = alloc((size_t)M_ROWS * 768);
    bf16* xd    = alloc((size_t)M_ROWS * 768);
    bf16* Qb    = alloc((size_t)M_ROWS * 768);
    bf16* QKVa  = alloc((size_t)M_ROWS * 2304); // cols 0..1535 kv, 1536..2303 q_a
    bf16* Ob    = alloc((size_t)M_ROWS * 768);
    float* pool0 = (float*)w; w += ((size_t)M_ROWS * 4 + 255) / 256 * 256;

    dim3 blk(256);
    dim3 blk512(512);
    transpose_w<<<dim3(24, 24), blk, 0, stream>>>(Wq_d,  WtQd, 768, 768);
    transpose_w<<<dim3(24, 48), blk, 0, stream>>>(Wkv_a, WtACat, 768, 1536);
    transpose_w<<<dim3(24, 24), blk, 0, stream>>>(Wq_a,  WtACat + (size_t)1536 * 768, 768, 768);
    transpose_w<<<dim3(24, 48), blk, 0, stream>>>(Wkv_d, WtKd, 768, 1536);
    transpose_w<<<dim3(24, 24), blk, 0, stream>>>(Wp_d,  WtPd, 768, 768);
    transpose_w<<<dim3(24, 24), blk, 0, stream>>>(Wp_a,  WtPa, 768, 768);
    conv_bias<<<dim3(6), blk, 0, stream>>>(bq_d, bkv_a, bq_a, bkv_d, bp_d, bp_a, biasAll);

    long total_chunks = (long)BATCH * 16 * S196 * 96;
    int  rblocks = (int)((total_chunks + 255) / 256);
    reorder_split<<<rblocks, blk, 0, stream>>>(x_in, xa, xd);
    pool_ad<<<M_ROWS / 4, blk, 0, stream>>>(xa, xd, pool0);

    const bf16* Bq_d   = biasAll;
    const bf16* Bkva_qa= biasAll + 768;   // 2304-wide: bkv_a | bq_a
    const bf16* Bkv_d  = biasAll + 3072;
    const bf16* Bp_d   = biasAll + 4608;
    const bf16* Bp_a   = biasAll + 5376;

    // BM=256 -> mTiles = 98; BN=256 -> nTiles: 3 (768), 6 (1536), 9 (2304)
    // Phase 1: Qb = xd@Wq_d ; QKVa = xa@[Wkv_a|Wq_a]
    gemm_bt<0><<<dim3(98 * 3), blk512, 0, stream>>>(xd, WtQd,  Bq_d,    nullptr, Qb,   768,  98, 3);
    gemm_bt<0><<<dim3(98 * 9), blk512, 0, stream>>>(xa, WtACat, Bkva_qa, nullptr, QKVa, 2304, 98, 9);
    attn_mfma<<<dim3(12, 128), blk, 0, stream>>>(Qb, 768, QKVa, 2304, Ob);
    gemm_bt<1><<<dim3(98 * 3), blk512, 0, stream>>>(Ob, WtPd, Bp_d, xd, xd, 768, 98, 3);

    // Phase 2: kv_d overwrites QKVa cols 0..1535 (kv_a is dead after attn1)
    gemm_bt<0><<<dim3(98 * 6), blk512, 0, stream>>>(xd, WtKd, Bkv_d, nullptr, QKVa, 2304, 98, 6);
    attn_mfma<<<dim3(12, 128), blk, 0, stream>>>(QKVa + 1536, 2304, QKVa, 2304, Ob);
    gemm_bt<2><<<dim3(98 * 3), blk512, 0, stream>>>(Ob, WtPa, Bp_a, xa, xa, 768, 98, 3);

    out_final<<<M_ROWS / 4, blk, 0, stream>>>(xa, xd, pool0, out);
}

// Round 3
// 863.972 us; speedup vs baseline: 1.1011x; 1.0843x over previous
//
#include <hip/hip_runtime.h>

typedef __bf16 bf16;
typedef __attribute__((ext_vector_type(8))) __bf16 bf16x8;
typedef __attribute__((ext_vector_type(4))) __bf16 bf16x4;
typedef __attribute__((ext_vector_type(2))) __bf16 bf16x2;
typedef __attribute__((ext_vector_type(4))) float f32x4;
typedef __attribute__((ext_vector_type(4))) unsigned int u32x4;

#define TOKENS 3136
#define CC 768
#define S196 196
#define M_ROWS 25088   // 16*8*196
#define BATCH 16

__device__ __forceinline__ float bf2f(bf16 x) { return (float)x; }
__device__ __forceinline__ bf16 f2bf(float x) { return (bf16)x; }

__device__ __forceinline__ float gelu_exact(float x) {
    return 0.5f * x * (1.0f + erff(x * 0.70710678118654752f));
}

__device__ __forceinline__ unsigned int packbf(float a, float b) {
    bf16x2 v; v[0] = (bf16)a; v[1] = (bf16)b;
    return __builtin_bit_cast(unsigned int, v);
}

// async global->LDS, 16B per lane; LDS dest = wave-uniform base + lane*16
#define GLOAD_LDS16(gp, lp) \
    __builtin_amdgcn_global_load_lds((const __attribute__((address_space(1))) void*)(gp), \
                                     (__attribute__((address_space(3))) void*)(lp), 16, 0, 0)

// ---------------------------------------------------------------------------
// Weight transpose + bf16 convert: Wt[n][k] = W[k][n]   (fp32 input)
// ---------------------------------------------------------------------------
__global__ __launch_bounds__(256)
void transpose_w(const float* __restrict__ W, bf16* __restrict__ Wt, int K, int N)
{
    __shared__ float tle[32][33];
    int k0 = blockIdx.x * 32, n0 = blockIdx.y * 32;
    int tx = threadIdx.x & 31, ty = threadIdx.x >> 5;   // 8 rows of 32
    for (int r = ty; r < 32; r += 8)
        tle[r][tx] = W[(long)(k0 + r) * N + n0 + tx];
    __syncthreads();
    for (int r = ty; r < 32; r += 8)
        Wt[(long)(n0 + r) * K + k0 + tx] = f2bf(tle[tx][r]);
}

// ---------------------------------------------------------------------------
// Bias convert (fp32 -> bf16) into packed ws array.
// Layout: [bq_d(768) | bkv_a(1536) | bq_a(768) | bkv_d(1536) | bp_d | bp_a]
// ---------------------------------------------------------------------------
__global__ __launch_bounds__(256)
void conv_bias(const float* b0, const float* b1, const float* b2,
               const float* b3, const float* b4, const float* b5,
               bf16* __restrict__ dst)
{
    const float* srcs[6] = {b0, b1, b2, b3, b4, b5};
    const int sizes[6]   = {768, 1536, 768, 1536, 768, 768};
    const int offs[6]    = {0, 768, 2304, 3072, 4608, 5376};
    int which = blockIdx.x;
    const float* s = srcs[which];
    int n = sizes[which];
    bf16* d = dst + offs[which];
    for (int i = threadIdx.x; i < n; i += 256)
        d[i] = f2bf(s[i]);
}

// ---------------------------------------------------------------------------
// Reorder x_in (b, nt, nh, nw, t, c) fp32 -> bf16 x_a / x_d rows
// ---------------------------------------------------------------------------
__global__ __launch_bounds__(256)
void reorder_split(const float* __restrict__ x_in, bf16* __restrict__ xa,
                   bf16* __restrict__ xd)
{
    long idx = (long)blockIdx.x * 256 + threadIdx.x;
    const long total = (long)BATCH * 16 * S196 * 96;
    if (idx >= total) return;
    int  c8  = (int)(idx % 96) * 8;
    long row = idx / 96;
    int  s   = (int)(row % S196);
    long r2  = row / S196;
    int  tt  = (int)(r2 & 15);
    int  b   = (int)(r2 >> 4);
    int  nt  = tt >> 2, t = tt & 3;
    int  nh  = s / 14,  nw = s % 14;
    long src  = ((long)b * TOKENS + ((nt * 14 + nh) * 14 + nw) * 4 + t) * CC + c8;
    bf16* dst = (tt & 1) ? xd : xa;
    long doff = ((long)(b * 8 + (tt >> 1)) * S196 + s) * CC + c8;
    const float* sp = x_in + src;
    f32x4 a = *(const f32x4*)sp;
    f32x4 c = *(const f32x4*)(sp + 4);
    bf16x8 v;
    v[0] = f2bf(a[0]); v[1] = f2bf(a[1]); v[2] = f2bf(a[2]); v[3] = f2bf(a[3]);
    v[4] = f2bf(c[0]); v[5] = f2bf(c[1]); v[6] = f2bf(c[2]); v[7] = f2bf(c[3]);
    *(bf16x8*)(dst + doff) = v;
}

// ---------------------------------------------------------------------------
// Row-sum helper: sum of 768 bf16 channels, one wave per row.
// ---------------------------------------------------------------------------
__device__ __forceinline__ float row_sum768(const bf16* __restrict__ p, int lane)
{
    float s = 0.f;
    bf16x8 v = *(const bf16x8*)(p + lane * 8);
    #pragma unroll
    for (int j = 0; j < 8; ++j) s += bf2f(v[j]);
    if (lane < 32) {
        bf16x8 w = *(const bf16x8*)(p + 512 + lane * 8);
        #pragma unroll
        for (int j = 0; j < 8; ++j) s += bf2f(w[j]);
    }
    #pragma unroll
    for (int off = 32; off; off >>= 1) s += __shfl_xor(s, off, 64);
    return s;
}

__global__ __launch_bounds__(256)
void pool_ad(const bf16* __restrict__ xa, const bf16* __restrict__ xd,
             float* __restrict__ pool0)
{
    int id = blockIdx.x * 4 + (threadIdx.x >> 6);
    int lane = threadIdx.x & 63;
    float sa = row_sum768(xa + (long)id * CC, lane);
    float sd = row_sum768(xd + (long)id * CC, lane);
    if (lane == 0) pool0[id] = (sa + sd) * (0.5f / 768.0f);
}

__global__ __launch_bounds__(256)
void out_final(const bf16* __restrict__ xa, const bf16* __restrict__ xd,
               const float* __restrict__ pool0, float* __restrict__ out)
{
    int id = blockIdx.x * 4 + (threadIdx.x >> 6);
    int lane = threadIdx.x & 63;
    float sa = row_sum768(xa + (long)id * CC, lane);
    float sd = row_sum768(xd + (long)id * CC, lane);
    if (lane == 0) {
        out[id]          = pool0[id] - sa * (1.0f / 768.0f);
        out[M_ROWS + id] = sd * (1.0f / 768.0f);
    }
}

// ---------------------------------------------------------------------------
// GEMM 128 (round-0 m97 structure): C = A(MxK) @ Bt(NxK)^T + bias.
// 128x128x32 tile, 256 threads, 16KB LDS -> ~3 blocks/CU.  Used for the
// four SMALL GEMM dispatches (grids 1176-2352 blocks: good tail behavior).
// EPI: 0 -> C = x ; 1 -> C = res - gelu(x) ; 2 -> C = res + gelu(x)
// ---------------------------------------------------------------------------
template<int EPI>
__global__ __launch_bounds__(256)
void gemm_bt128(const bf16* __restrict__ A, const bf16* __restrict__ Bt,
                const bf16* __restrict__ bias, const bf16* __restrict__ res,
                bf16* __restrict__ C, int ldc, int K, int mTiles, int nTiles)
{
    constexpr int BM = 128, BK = 32;
    __shared__ alignas(16) bf16 sA[BM * BK];
    __shared__ alignas(16) bf16 sB[BM * BK];
    const int tid  = threadIdx.x;
    const int lane = tid & 63, wave = tid >> 6;
    const int wm   = wave >> 1, wn = wave & 1;
    const int quad = lane >> 4, l16 = lane & 15;

    const int GM = 16;
    int pid   = blockIdx.x;
    int group = GM * nTiles;
    int gid   = pid / group;
    int rem   = pid - gid * group;
    int first = gid * GM;
    int gm    = (mTiles - first < GM) ? (mTiles - first) : GM;
    int bm    = first + rem % gm;
    int bn    = rem / gm;

    const long m0 = (long)bm * BM;
    const long n0 = (long)bn * BM;

    f32x4 acc[4][4] = {};

    for (int kt = 0; kt < K; kt += BK) {
        if (kt) __syncthreads();
        #pragma unroll
        for (int c = 0; c < 2; ++c) {
            int ci = (wave * 2 + c) * 64 + lane;
            int r  = ci >> 2, kc = ci & 3;
            const bf16* ga = A  + (m0 + r) * K + kt + kc * 8;
            const bf16* gb = Bt + (n0 + r) * K + kt + kc * 8;
            bf16* la = sA + (wave * 2 + c) * 512;
            bf16* lb = sB + (wave * 2 + c) * 512;
            GLOAD_LDS16(ga, la);
            GLOAD_LDS16(gb, lb);
        }
        __syncthreads();

        bf16x8 af[4], bfr[4];
        #pragma unroll
        for (int mi = 0; mi < 4; ++mi)
            af[mi] = *(const bf16x8*)(sA + (wm * 64 + mi * 16 + l16) * BK + quad * 8);
        #pragma unroll
        for (int ni = 0; ni < 4; ++ni)
            bfr[ni] = *(const bf16x8*)(sB + (wn * 64 + ni * 16 + l16) * BK + quad * 8);
        #pragma unroll
        for (int mi = 0; mi < 4; ++mi)
            #pragma unroll
            for (int ni = 0; ni < 4; ++ni)
                acc[mi][ni] = __builtin_amdgcn_mfma_f32_16x16x32_bf16(af[mi], bfr[ni], acc[mi][ni], 0, 0, 0);
    }

    #pragma unroll
    for (int mi = 0; mi < 4; ++mi) {
        #pragma unroll
        for (int ni = 0; ni < 4; ++ni) {
            int mg = (int)m0 + wm * 64 + mi * 16 + quad * 4;
            int ng = (int)n0 + wn * 64 + ni * 16 + l16;
            float bn_ = bf2f(bias[ng]);
            #pragma unroll
            for (int r = 0; r < 4; ++r) {
                float x = acc[mi][ni][r] + bn_;
                long off = (long)(mg + r) * ldc + ng;
                if (EPI == 0)      C[off] = f2bf(x);
                else if (EPI == 1) C[off] = f2bf(bf2f(res[off]) - gelu_exact(x));
                else               C[off] = f2bf(bf2f(res[off]) + gelu_exact(x));
            }
        }
    }
}

// ---------------------------------------------------------------------------
// GEMM 256 (4-phase counted-vmcnt): big dispatch only (nTiles=9, 882 blocks).
// BM=BN=256, BK=64, 512 thr = 8 waves (2M x 4N), per-wave 128x64 (8x4 frags).
// LDS: 4 K-half-slots per operand, 16KB each (128 KB total).  Slot for
// (t,kk) = (2t+kk)&3, reused by (t+2,kk).
//
// LDS geometry (the round-1-verified 0-conflict form): each half-slot is
// 128 LINES x 128B; line L holds global rows {2L, 2L+1} (32 k-elems each).
// Logical chunk c = (row&1)*4 + k8 (c in 0..7, 16B units); physical pos =
// c ^ (L&7)  -- 3-bit XOR over full 128B lines => uniform 8 lanes per 4-bank
// group on every wave-wide ds_read_b128 (measured 0 conflicts in round 1).
// Staging pre-swizzles the GLOBAL source address; LDS dest stays linear.
//
// Phases per K-tile t: ph0=(h0,k0) ph1=(h1,k0) ph2=(h0,k1) ph3=(h1,k1);
// each = { ds_read frags ; issue one 2-load stage ; s_barrier ; setprio(1)
// 16 MFMA setprio(0) ; [counted vmcnt] ; s_barrier }.  vmcnt(8) twice per
// K-tile (in-order vmem retirement makes the gating exact); full drain only
// at the tail.  asm "memory" clobbers provide all required orderings.
// ---------------------------------------------------------------------------
template<int EPI>
__global__ __launch_bounds__(512, 2)
void gemm_bt256(const bf16* __restrict__ A, const bf16* __restrict__ Bt,
                const bf16* __restrict__ bias, const bf16* __restrict__ res,
                bf16* __restrict__ C, int ldc, int mTiles, int nTiles)
{
    constexpr int K = 768, NKT = 12;
    __shared__ alignas(16) bf16 sA[4][8192];  // 4 x 16 KB A half-slots
    __shared__ alignas(16) bf16 sB[4][8192];  // 4 x 16 KB B half-slots
    const int tid  = threadIdx.x;
    const int lane = tid & 63, wave = tid >> 6;
    const int wm   = wave >> 2, wn = wave & 3;   // 2M x 4N wave grid
    const int quad = lane >> 4, l16 = lane & 15;

    // bijective XCD chunking (m204): consecutive wgid ranges land on one XCD
    int nwg  = (int)gridDim.x;
    int orig = (int)blockIdx.x;
    int q8 = nwg >> 3, r8 = nwg & 7, xcd = orig & 7;
    int pid = (xcd < r8 ? xcd * (q8 + 1) : r8 * (q8 + 1) + (xcd - r8) * q8)
              + (orig >> 3);

    // GROUP_M swizzle for panel reuse within the XCD's L2
    const int GM = 8;
    int group = GM * nTiles;
    int gid   = pid / group;
    int rem   = pid - gid * group;
    int first = gid * GM;
    int gm    = (mTiles - first < GM) ? (mTiles - first) : GM;
    int bm    = first + rem % gm;
    int bn    = rem / gm;

    const long m0 = (long)bm * 256;
    const long n0 = (long)bn * 256;

    // ---- ds_read offsets (element units within a half-slot) ----
    // row R = rbase + l16 (rbase mult of 16): line = R>>1 = rbase/2 + (l16>>1);
    // line&7 = l16>>1; c = (l16&1)*4 + quad; pos = c ^ (l16>>1).
    const int lh  = l16 >> 1;
    const int px  = ((l16 & 1) << 2) | quad;
    const int pxl = (px ^ lh) * 8;
    const int aoffA = (wm * 64 + lh) * 64 + pxl;   // + mf*512 per frag
    const int aoffB = (wn * 32 + lh) * 64 + pxl;   // + nf*512 per frag

    // ---- staging constants ----
    // gload j: thread tid writes 16B chunk g = j*512+tid; L = g>>3, pos = tid&7;
    // c = pos ^ (L&7) = (tid&7) ^ ((tid>>3)&7);
    // global row = j*128 + 2*(tid>>3) + (c>>2), k8 = c&3.
    const int  cg  = (tid & 7) ^ ((tid >> 3) & 7);
    const int  rr  = ((tid >> 3) << 1) + (cg >> 2);
    const long soA0 = (long)rr * K + (cg & 3) * 8;          // j=0
    const long soA1 = (long)(128 + rr) * K + (cg & 3) * 8;  // j=1
    const int  ldd0 = wave * 512, ldd1 = 4096 + wave * 512;
    const bf16* Ab = A  + m0 * K;
    const bf16* Bb = Bt + n0 * K;

    f32x4 acc[8][4] = {};

    #define STG_A(slot, koff) do { \
        GLOAD_LDS16(Ab + (koff) + soA0, &sA[slot][ldd0]); \
        GLOAD_LDS16(Ab + (koff) + soA1, &sA[slot][ldd1]); } while (0)
    #define STG_B(slot, koff) do { \
        GLOAD_LDS16(Bb + (koff) + soA0, &sB[slot][ldd0]); \
        GLOAD_LDS16(Bb + (koff) + soA1, &sB[slot][ldd1]); } while (0)

    // prologue: halves (0,Ak0)(0,Bk0)(0,Ak1)(0,Bk1)(1,Ak0)(1,Bk0)
    STG_A(0, 0);  STG_B(0, 0);
    STG_A(1, 32); STG_B(1, 32);
    STG_A(2, 64); STG_B(2, 64);
    asm volatile("s_waitcnt vmcnt(8)" ::: "memory");   // (0,k0) A+B landed
    __builtin_amdgcn_s_barrier();

    #define MFMA16(H) do { \
        __builtin_amdgcn_s_setprio(1); \
        _Pragma("unroll") \
        for (int mf = 0; mf < 4; ++mf) \
            _Pragma("unroll") \
            for (int nf = 0; nf < 4; ++nf) \
                acc[(H)*4 + mf][nf] = __builtin_amdgcn_mfma_f32_16x16x32_bf16( \
                    a[mf], b[nf], acc[(H)*4 + mf][nf], 0, 0, 0); \
        __builtin_amdgcn_s_setprio(0); } while (0)

    #pragma unroll 2
    for (int t = 0; t < NKT; ++t) {
        const int sl0 = (2 * t) & 3;        // (t, k0)
        const int sl1 = (2 * t + 1) & 3;    // (t, k1)
        const int slN = (2 * t + 3) & 3;    // (t+1, k1)
        bf16x8 a[4], b[4];

        // ---- ph0: (h0, k0) ----
        #pragma unroll
        for (int mf = 0; mf < 4; ++mf) a[mf] = *(const bf16x8*)(&sA[sl0][mf * 512 + aoffA]);
        #pragma unroll
        for (int nf = 0; nf < 4; ++nf) b[nf] = *(const bf16x8*)(&sB[sl0][nf * 512 + aoffB]);
        if (t + 1 < NKT) STG_A(slN, (t + 1) * 64 + 32);
        __builtin_amdgcn_s_barrier();
        MFMA16(0);
        __builtin_amdgcn_s_barrier();

        // ---- ph1: (h1, k0), B regs reused ----
        #pragma unroll
        for (int mf = 0; mf < 4; ++mf) a[mf] = *(const bf16x8*)(&sA[sl0][2048 + mf * 512 + aoffA]);
        if (t + 1 < NKT) STG_B(slN, (t + 1) * 64 + 32);
        __builtin_amdgcn_s_barrier();
        MFMA16(1);
        if (t + 1 < NKT) asm volatile("s_waitcnt vmcnt(8)" ::: "memory");
        else             asm volatile("s_waitcnt vmcnt(0)" ::: "memory");
        __builtin_amdgcn_s_barrier();

        // ---- ph2: (h0, k1) ----
        #pragma unroll
        for (int mf = 0; mf < 4; ++mf) a[mf] = *(const bf16x8*)(&sA[sl1][mf * 512 + aoffA]);
        #pragma unroll
        for (int nf = 0; nf < 4; ++nf) b[nf] = *(const bf16x8*)(&sB[sl1][nf * 512 + aoffB]);
        if (t + 2 < NKT) STG_A(sl0, (t + 2) * 64);
        __builtin_amdgcn_s_barrier();
        MFMA16(0);
        __builtin_amdgcn_s_barrier();

        // ---- ph3: (h1, k1), B regs reused ----
        #pragma unroll
        for (int mf = 0; mf < 4; ++mf) a[mf] = *(const bf16x8*)(&sA[sl1][2048 + mf * 512 + aoffA]);
        if (t + 2 < NKT) STG_B(sl0, (t + 2) * 64);
        __builtin_amdgcn_s_barrier();
        MFMA16(1);
        if      (t + 2 < NKT) asm volatile("s_waitcnt vmcnt(8)" ::: "memory");
        else if (t + 1 < NKT) asm volatile("s_waitcnt vmcnt(4)" ::: "memory");
        __builtin_amdgcn_s_barrier();
    }
    #undef STG_A
    #undef STG_B
    #undef MFMA16

    // Epilogue. Frag D layout: col = l16 (n), row = quad*4 + r (m)
    #pragma unroll
    for (int mf = 0; mf < 8; ++mf) {
        #pragma unroll
        for (int nf = 0; nf < 4; ++nf) {
            int mg = (int)m0 + wm * 128 + mf * 16 + quad * 4;
            int ng = (int)n0 + wn * 64 + nf * 16 + l16;
            float bn_ = bf2f(bias[ng]);
            #pragma unroll
            for (int r = 0; r < 4; ++r) {
                float x = acc[mf][nf][r] + bn_;
                long off = (long)(mg + r) * ldc + ng;
                if (EPI == 0)      C[off] = f2bf(x);
                else if (EPI == 1) C[off] = f2bf(bf2f(res[off]) - gelu_exact(x));
                else               C[off] = f2bf(bf2f(res[off]) + gelu_exact(x));
            }
        }
    }
}

// ---------------------------------------------------------------------------
// MFMA attention, stride-parameterized. One block per (head h, instance bj).
// ---------------------------------------------------------------------------
#define KSTR 72
#define VSTR 264

__global__ __launch_bounds__(256)
void attn_mfma(const bf16* __restrict__ Q, int ldq,
               const bf16* __restrict__ KV, int ldkv,
               bf16* __restrict__ O)
{
    const int h  = blockIdx.x;   // 12
    const int bj = blockIdx.y;   // 128
    __shared__ alignas(16) bf16 Ks[208 * KSTR];
    __shared__ alignas(16) bf16 Vt[64 * VSTR];
    const int tid = threadIdx.x, lane = tid & 63, wave = tid >> 6;
    const int quad = lane >> 4, l16 = lane & 15;

    const bf16* qg = Q  + (long)bj * S196 * ldq  + h * 64;
    const bf16* kg = KV + (long)bj * S196 * ldkv + h * 64;
    const bf16* vg = kg + CC;

    for (int i = tid; i < 208 * 8; i += 256) {
        int r = i >> 3, c8 = (i & 7) * 8;
        bf16x8 v = {};
        if (r < S196) v = *(const bf16x8*)(kg + (long)r * ldkv + c8);
        *(bf16x8*)(Ks + r * KSTR + c8) = v;
    }
    for (int i = tid; i < 256 * 8; i += 256) {
        int g   = i >> 6;
        int c8  = (g & 7) * 8;
        int tok = (g >> 3) * 64 + (i & 63);
        bf16x8 v = {};
        if (tok < S196) v = *(const bf16x8*)(vg + (long)tok * ldkv + c8);
        #pragma unroll
        for (int j = 0; j < 8; ++j)
            Vt[(c8 + j) * VSTR + tok] = v[j];
    }
    __syncthreads();

    for (int qt = wave; qt < 13; qt += 4) {
        int qrow = qt * 16 + l16; if (qrow > 195) qrow = 195;
        const bf16* qrp = qg + (long)qrow * ldq + quad * 8;
        bf16x8 qf0 = *(const bf16x8*)(qrp);
        bf16x8 qf1 = *(const bf16x8*)(qrp + 32);

        f32x4 st[13];
        #pragma unroll
        for (int rt = 0; rt < 13; ++rt) st[rt] = (f32x4){0.f, 0.f, 0.f, 0.f};
        #pragma unroll
        for (int rt = 0; rt < 13; ++rt) {
            const bf16* kb = Ks + (rt * 16 + l16) * KSTR + quad * 8;
            bf16x8 kf0 = *(const bf16x8*)(kb);
            bf16x8 kf1 = *(const bf16x8*)(kb + 32);
            st[rt] = __builtin_amdgcn_mfma_f32_16x16x32_bf16(kf0, qf0, st[rt], 0, 0, 0);
            st[rt] = __builtin_amdgcn_mfma_f32_16x16x32_bf16(kf1, qf1, st[rt], 0, 0, 0);
        }

        const float SC = 0.125f;
        #pragma unroll
        for (int rt = 0; rt < 13; ++rt) {
            st[rt][0] *= SC; st[rt][1] *= SC; st[rt][2] *= SC; st[rt][3] *= SC;
        }
        if (quad != 0)
            st[12] = (f32x4){-1e30f, -1e30f, -1e30f, -1e30f};

        float m = -1e30f;
        #pragma unroll
        for (int rt = 0; rt < 13; ++rt)
            m = fmaxf(m, fmaxf(fmaxf(st[rt][0], st[rt][1]), fmaxf(st[rt][2], st[rt][3])));
        m = fmaxf(m, __shfl_xor(m, 16, 64));
        m = fmaxf(m, __shfl_xor(m, 32, 64));
        float sum = 0.f;
        #pragma unroll
        for (int rt = 0; rt < 13; ++rt) {
            st[rt][0] = __expf(st[rt][0] - m);
            st[rt][1] = __expf(st[rt][1] - m);
            st[rt][2] = __expf(st[rt][2] - m);
            st[rt][3] = __expf(st[rt][3] - m);
            sum += st[rt][0] + st[rt][1] + st[rt][2] + st[rt][3];
        }
        sum += __shfl_xor(sum, 16, 64);
        sum += __shfl_xor(sum, 32, 64);
        float inv = 1.0f / sum;

        unsigned int pk[13][2];
        #pragma unroll
        for (int rt = 0; rt < 13; ++rt) {
            pk[rt][0] = packbf(st[rt][0] * inv, st[rt][1] * inv);
            pk[rt][1] = packbf(st[rt][2] * inv, st[rt][3] * inv);
        }

        f32x4 ot[4];
        #pragma unroll
        for (int dt = 0; dt < 4; ++dt) ot[dt] = (f32x4){0.f, 0.f, 0.f, 0.f};
        #pragma unroll
        for (int c = 0; c < 7; ++c) {
            u32x4 fp;
            #pragma unroll
            for (int jp = 0; jp < 4; ++jp) {
                int jh = jp >> 1, rp = jp & 1;
                int srcb = ((((quad & 1) << 1) + jh) << 6) | (l16 << 2);
                int a = __builtin_amdgcn_ds_bpermute(srcb, (int)pk[2 * c][rp]);
                int b = (c < 6) ? __builtin_amdgcn_ds_bpermute(srcb, (int)pk[2 * c + 1][rp]) : 0;
                fp[jp] = (quad >> 1) ? (unsigned int)b : (unsigned int)a;
            }
            bf16x8 pB = __builtin_bit_cast(bf16x8, fp);
            #pragma unroll
            for (int dt = 0; dt < 4; ++dt) {
                bf16x8 vf = *(const bf16x8*)(Vt + (dt * 16 + l16) * VSTR + c * 32 + quad * 8);
                ot[dt] = __builtin_amdgcn_mfma_f32_16x16x32_bf16(vf, pB, ot[dt], 0, 0, 0);
            }
        }

        int token = qt * 16 + l16;
        if (token < S196) {
            bf16* op = O + ((long)bj * S196 + token) * CC + h * 64 + quad * 4;
            #pragma unroll
            for (int dt = 0; dt < 4; ++dt) {
                bf16x4 v;
                v[0] = f2bf(ot[dt][0]); v[1] = f2bf(ot[dt][1]);
                v[2] = f2bf(ot[dt][2]); v[3] = f2bf(ot[dt][3]);
                *(bf16x4*)(op + dt * 16) = v;
            }
        }
    }
}

// ---------------------------------------------------------------------------
extern "C" void kernel_launch(void* const* d_in, const int* in_sizes, int n_in,
                              void* d_out, int out_size, void* d_ws, size_t ws_size,
                              hipStream_t stream)
{
    const float* x_in  = (const float*)d_in[0];
    const float* Wq_d  = (const float*)d_in[1];
    const float* bq_d  = (const float*)d_in[2];
    const float* Wkv_a = (const float*)d_in[3];
    const float* bkv_a = (const float*)d_in[4];
    const float* Wq_a  = (const float*)d_in[5];
    const float* bq_a  = (const float*)d_in[6];
    const float* Wkv_d = (const float*)d_in[7];
    const float* bkv_d = (const float*)d_in[8];
    const float* Wp_d  = (const float*)d_in[9];
    const float* bp_d  = (const float*)d_in[10];
    const float* Wp_a  = (const float*)d_in[11];
    const float* bp_a  = (const float*)d_in[12];
    float* out = (float*)d_out;

    char* w = (char*)d_ws;
    auto alloc = [&](size_t elems) {
        bf16* p = (bf16*)w;
        w += ((elems * 2 + 255) / 256) * 256;
        return p;
    };
    bf16* biasAll = alloc(6144);
    bf16* WtQd  = alloc((size_t)768 * 768);
    bf16* WtACat= alloc((size_t)2304 * 768);   // [Wkv_a^T ; Wq_a^T]
    bf16* WtKd  = alloc((size_t)1536 * 768);
    bf16* WtPd  = alloc((size_t)768 * 768);
    bf16* WtPa  = alloc((size_t)768 * 768);
    bf16* xa    = alloc((size_t)M_ROWS * 768);
    bf16* xd    = alloc((size_t)M_ROWS * 768);
    bf16* Qb    = alloc((size_t)M_ROWS * 768);
    bf16* QKVa  = alloc((size_t)M_ROWS * 2304); // cols 0..1535 kv, 1536..2303 q_a
    bf16* Ob    = alloc((size_t)M_ROWS * 768);
    float* pool0 = (float*)w; w += ((size_t)M_ROWS * 4 + 255) / 256 * 256;

    dim3 blk(256);
    dim3 blk512(512);
    transpose_w<<<dim3(24, 24), blk, 0, stream>>>(Wq_d,  WtQd, 768, 768);
    transpose_w<<<dim3(24, 48), blk, 0, stream>>>(Wkv_a, WtACat, 768, 1536);
    transpose_w<<<dim3(24, 24), blk, 0, stream>>>(Wq_a,  WtACat + (size_t)1536 * 768, 768, 768);
    transpose_w<<<dim3(24, 48), blk, 0, stream>>>(Wkv_d, WtKd, 768, 1536);
    transpose_w<<<dim3(24, 24), blk, 0, stream>>>(Wp_d,  WtPd, 768, 768);
    transpose_w<<<dim3(24, 24), blk, 0, stream>>>(Wp_a,  WtPa, 768, 768);
    conv_bias<<<dim3(6), blk, 0, stream>>>(bq_d, bkv_a, bq_a, bkv_d, bp_d, bp_a, biasAll);

    long total_chunks = (long)BATCH * 16 * S196 * 96;
    int  rblocks = (int)((total_chunks + 255) / 256);
    reorder_split<<<rblocks, blk, 0, stream>>>(x_in, xa, xd);
    pool_ad<<<M_ROWS / 4, blk, 0, stream>>>(xa, xd, pool0);

    const bf16* Bq_d   = biasAll;
    const bf16* Bkva_qa= biasAll + 768;   // 2304-wide: bkv_a | bq_a
    const bf16* Bkv_d  = biasAll + 3072;
    const bf16* Bp_d   = biasAll + 4608;
    const bf16* Bp_a   = biasAll + 5376;

    // Phase 1: Qb = xd@Wq_d (128² kernel) ; QKVa = xa@[Wkv_a|Wq_a] (256² kernel)
    gemm_bt128<0><<<dim3(196 * 6), blk, 0, stream>>>(xd, WtQd, Bq_d, nullptr, Qb, 768, 768, 196, 6);
    gemm_bt256<0><<<dim3(98 * 9), blk512, 0, stream>>>(xa, WtACat, Bkva_qa, nullptr, QKVa, 2304, 98, 9);
    attn_mfma<<<dim3(12, 128), blk, 0, stream>>>(Qb, 768, QKVa, 2304, Ob);
    gemm_bt128<1><<<dim3(196 * 6), blk, 0, stream>>>(Ob, WtPd, Bp_d, xd, xd, 768, 768, 196, 6);

    // Phase 2: kv_d overwrites QKVa cols 0..1535 (kv_a is dead after attn1)
    gemm_bt128<0><<<dim3(196 * 12), blk, 0, stream>>>(xd, WtKd, Bkv_d, nullptr, QKVa, 2304, 768, 196, 12);
    attn_mfma<<<dim3(12, 128), blk, 0, stream>>>(QKVa + 1536, 2304, QKVa, 2304, Ob);
    gemm_bt128<2><<<dim3(196 * 6), blk, 0, stream>>>(Ob, WtPa, Bp_a, xa, xa, 768, 768, 196, 6);

    out_final<<<M_ROWS / 4, blk, 0, stream>>>(xa, xd, pool0, out);
}